// Round 1
// baseline (580.351 us; speedup 1.0000x reference)
//
#include <hip/hip_runtime.h>

// ---------------- types / helpers ----------------
typedef __attribute__((ext_vector_type(4))) float f32x4;
typedef __attribute__((ext_vector_type(8))) short s16x8;
typedef __attribute__((ext_vector_type(8))) __bf16 bf16x8;

__device__ __forceinline__ unsigned short f2b(float f) {
  union { float f; unsigned u; } x; x.f = f;
  unsigned r = x.u + 0x7fffu + ((x.u >> 16) & 1u);
  return (unsigned short)(r >> 16);
}
__device__ __forceinline__ float b2f(unsigned short u) {
  union { unsigned u; float f; } x; x.u = ((unsigned)u) << 16;
  return x.f;
}
__device__ __forceinline__ void gld16(const void* g, void* l) {
  __builtin_amdgcn_global_load_lds(
      (const __attribute__((address_space(1))) unsigned int*)g,
      (__attribute__((address_space(3))) unsigned int*)l, 16, 0, 0);
}
__device__ __forceinline__ f32x4 mfma_bf16(s16x8 a, s16x8 b, f32x4 c) {
  return __builtin_amdgcn_mfma_f32_16x16x32_bf16(
      __builtin_bit_cast(bf16x8, a), __builtin_bit_cast(bf16x8, b), c, 0, 0, 0);
}

// ---------------- conversion kernels ----------------
__global__ void k_f32_to_bf16(const float* __restrict__ in,
                              unsigned short* __restrict__ out, int n4) {
  int i = blockIdx.x * blockDim.x + threadIdx.x;
  if (i >= n4) return;
  float4 v = ((const float4*)in)[i];
  ushort4 o;
  o.x = f2b(v.x); o.y = f2b(v.y); o.z = f2b(v.z); o.w = f2b(v.w);
  ((ushort4*)out)[i] = o;
}

// W [K][N] fp32 -> WT [N][K] bf16
__global__ void k_transpose_w(const float* __restrict__ W,
                              unsigned short* __restrict__ WT, int K, int N) {
  __shared__ float tile[32][33];
  int n0 = blockIdx.x * 32, k0 = blockIdx.y * 32;
  int tx = threadIdx.x & 31, ty = threadIdx.x >> 5;
#pragma unroll
  for (int i = 0; i < 32; i += 8)
    tile[ty + i][tx] = W[(size_t)(k0 + ty + i) * N + n0 + tx];
  __syncthreads();
#pragma unroll
  for (int i = 0; i < 32; i += 8)
    WT[(size_t)(n0 + ty + i) * K + k0 + tx] = f2b(tile[tx][ty + i]);
}

// ---------------- GEMM: C[M,N] = A[M,K](bf16) * BT[N,K](bf16)^T ----------------
// EPI 0: outb = bf16(acc*alpha).  EPI 1: outf = acc + bias[n] + b2f(ipadd[m,n]).
template <int EPI>
__global__ __launch_bounds__(256) void k_gemm_bt(
    const unsigned short* __restrict__ A, const unsigned short* __restrict__ BT,
    int M, int N, int K, float alpha,
    unsigned short* __restrict__ outb,
    float* __restrict__ outf, const float* __restrict__ bias,
    const unsigned short* __restrict__ ipadd) {
  const int tid = threadIdx.x;
  const int l = tid & 63;
  const int w = tid >> 6;
  const int wr = w >> 1, wc = w & 1;
  const int m0 = blockIdx.y * 128, n0 = blockIdx.x * 128;
  __shared__ unsigned short As[128 * 32];
  __shared__ unsigned short Bs[128 * 32];
  f32x4 acc[4][4] = {};

  const int o0 = tid * 16;       // byte offset in first 4KB
  const int o1 = o0 + 4096;      // second 4KB
  const int ra0 = o0 >> 6, ca0 = (o0 & 63) >> 1;
  const int ra1 = o1 >> 6, ca1 = (o1 & 63) >> 1;
  int ga0 = m0 + ra0; if (ga0 >= M) ga0 = M - 1;
  int ga1 = m0 + ra1; if (ga1 >= M) ga1 = M - 1;
  const unsigned short* Ar0 = A + (size_t)ga0 * K + ca0;
  const unsigned short* Ar1 = A + (size_t)ga1 * K + ca1;
  const unsigned short* Br0 = BT + (size_t)(n0 + ra0) * K + ca0;
  const unsigned short* Br1 = BT + (size_t)(n0 + ra1) * K + ca1;

  for (int k0 = 0; k0 < K; k0 += 32) {
    gld16(Ar0 + k0, &As[o0 >> 1]);
    gld16(Ar1 + k0, &As[o1 >> 1]);
    gld16(Br0 + k0, &Bs[o0 >> 1]);
    gld16(Br1 + k0, &Bs[o1 >> 1]);
    __syncthreads();
    s16x8 af[4], bfr[4];
#pragma unroll
    for (int mi = 0; mi < 4; ++mi)
      af[mi] = *(const s16x8*)&As[(wr * 64 + mi * 16 + (l & 15)) * 32 + (l >> 4) * 8];
#pragma unroll
    for (int ni = 0; ni < 4; ++ni)
      bfr[ni] = *(const s16x8*)&Bs[(wc * 64 + ni * 16 + (l & 15)) * 32 + (l >> 4) * 8];
#pragma unroll
    for (int mi = 0; mi < 4; ++mi)
#pragma unroll
      for (int ni = 0; ni < 4; ++ni)
        acc[mi][ni] = mfma_bf16(af[mi], bfr[ni], acc[mi][ni]);
    __syncthreads();
  }

#pragma unroll
  for (int mi = 0; mi < 4; ++mi) {
    const int mbase = m0 + wr * 64 + mi * 16 + (l >> 4) * 4;
#pragma unroll
    for (int ni = 0; ni < 4; ++ni) {
      const int ncol = n0 + wc * 64 + ni * 16 + (l & 15);
#pragma unroll
      for (int r = 0; r < 4; ++r) {
        int m = mbase + r;
        if (m < M) {
          if constexpr (EPI == 0) {
            outb[(size_t)m * N + ncol] = f2b(acc[mi][ni][r] * alpha);
          } else {
            outf[(size_t)m * N + ncol] =
                acc[mi][ni][r] + bias[ncol] + b2f(ipadd[(size_t)m * N + ncol]);
          }
        }
      }
    }
  }
}

// ---------------- fused attention (main stream + IP stream) ----------------
// grid: (64 qtiles, 20 heads, 4 batch); 256 threads (4 waves x 16 q-rows)
__global__ __launch_bounds__(256) void k_attn(
    const unsigned short* __restrict__ Q,    // [16384][1280], pre-scaled by 1/8
    const unsigned short* __restrict__ Kb,   // [308][1280]
    const unsigned short* __restrict__ Vb,   // [308][1280]
    const unsigned short* __restrict__ Kip,  // [64][1280]
    const unsigned short* __restrict__ Vip,  // [64][1280]
    const float* __restrict__ mask,          // [4096][77]
    unsigned short* __restrict__ Oattn,      // [16384][1280]
    unsigned short* __restrict__ Oip) {      // [16384][1280]
  const int qt = blockIdx.x, h = blockIdx.y, b = blockIdx.z;
  const int tid = threadIdx.x, l = tid & 63, w = tid >> 6;
  const int m0 = b * 4096 + qt * 64;

  __shared__ unsigned short Qs[64][72];     // pad 72: 2-way max on b128 reads
  __shared__ unsigned short Ks[80][72];
  __shared__ unsigned short VTs[64][104];   // V transposed [d][t], t padded to 96
  __shared__ unsigned short Ps[64][104];    // probs bf16, cols 77..95 zeroed
  __shared__ unsigned short Kips[16][72];
  __shared__ unsigned short VipTs[64][40];  // Vip transposed [d][t], t padded to 32
  __shared__ unsigned short P2s[64][40];

  // stage Q tile (64 rows x 64 cols)
#pragma unroll
  for (int i = 0; i < 2; ++i) {
    int o = (tid + i * 256) * 16;
    int r = o >> 7, ce = (o & 127) >> 1;
    int4 v = *(const int4*)(Q + (size_t)(m0 + r) * 1280 + h * 64 + ce);
    *(int4*)&Qs[r][ce] = v;
  }
  // stage K (80 rows; rows >= 77 zero)
#pragma unroll
  for (int i = 0; i < 3; ++i) {
    int o = (tid + i * 256) * 16;
    if (o < 80 * 128) {
      int r = o >> 7, ce = (o & 127) >> 1;
      int4 v = {0, 0, 0, 0};
      if (r < 77) v = *(const int4*)(Kb + (size_t)(b * 77 + r) * 1280 + h * 64 + ce);
      *(int4*)&Ks[r][ce] = v;
    }
  }
  // stage V transposed, zero cols t in [77,96)
  for (int idx = tid; idx < 64 * 96; idx += 256) {
    int t = idx >> 6, d = idx & 63;
    unsigned short v = 0;
    if (t < 77) v = Vb[(size_t)(b * 77 + t) * 1280 + h * 64 + d];
    VTs[d][t] = v;
  }
  // stage Kip
  for (int idx = tid; idx < 16 * 64; idx += 256) {
    int t = idx >> 6, d = idx & 63;
    Kips[t][d] = Kip[(size_t)(b * 16 + t) * 1280 + h * 64 + d];
  }
  // stage Vip transposed, zero cols t in [16,32)
  for (int idx = tid; idx < 64 * 32; idx += 256) {
    int t = idx >> 6, d = idx & 63;
    unsigned short v = 0;
    if (t < 16) v = Vip[(size_t)(b * 16 + t) * 1280 + h * 64 + d];
    VipTs[d][t] = v;
  }
  __syncthreads();

  const int r0 = w * 16;
  const int lr = l & 15, lg = l >> 4;
  s16x8 aq0 = *(const s16x8*)&Qs[r0 + lr][lg * 8];
  s16x8 aq1 = *(const s16x8*)&Qs[r0 + lr][32 + lg * 8];

  // QK^T: 5 col-tiles of 16 (t=0..79), K rows 77..79 are zeros
  f32x4 sc[5];
#pragma unroll
  for (int t5 = 0; t5 < 5; ++t5) {
    s16x8 b0 = *(const s16x8*)&Ks[t5 * 16 + lr][lg * 8];
    s16x8 b1 = *(const s16x8*)&Ks[t5 * 16 + lr][32 + lg * 8];
    f32x4 c = {};
    c = mfma_bf16(aq0, b0, c);
    c = mfma_bf16(aq1, b1, c);
    sc[t5] = c;
  }
  // IP scores (reuse Q frags)
  f32x4 sip = {};
  {
    s16x8 b0 = *(const s16x8*)&Kips[lr][lg * 8];
    s16x8 b1 = *(const s16x8*)&Kips[lr][32 + lg * 8];
    sip = mfma_bf16(aq0, b0, sip);
    sip = mfma_bf16(aq1, b1, sip);
  }

  // softmax (rows live in the 16-lane column group), post-softmax mask multiply
#pragma unroll
  for (int r = 0; r < 4; ++r) {
    float mx = fmaxf(fmaxf(fmaxf(sc[0][r], sc[1][r]), fmaxf(sc[2][r], sc[3][r])), sc[4][r]);
    mx = fmaxf(mx, __shfl_xor(mx, 1));
    mx = fmaxf(mx, __shfl_xor(mx, 2));
    mx = fmaxf(mx, __shfl_xor(mx, 4));
    mx = fmaxf(mx, __shfl_xor(mx, 8));
    float p[5], sm = 0.f;
#pragma unroll
    for (int t5 = 0; t5 < 5; ++t5) {
      bool valid = (t5 < 4) | (lr < 13);  // t = t5*16+lr < 77
      p[t5] = valid ? __expf(sc[t5][r] - mx) : 0.f;
      sm += p[t5];
    }
    sm += __shfl_xor(sm, 1);
    sm += __shfl_xor(sm, 2);
    sm += __shfl_xor(sm, 4);
    sm += __shfl_xor(sm, 8);
    const float inv = 1.0f / sm;
    const int row = r0 + lg * 4 + r;
    const int qg = qt * 64 + row;
#pragma unroll
    for (int t5 = 0; t5 < 5; ++t5) {
      int t = t5 * 16 + lr;
      float pf = 0.f;
      if (t < 77) pf = p[t5] * inv * mask[qg * 77 + t];
      Ps[row][t] = f2b(pf);
    }
    Ps[row][80 + lr] = 0;  // zero pad cols 80..95

    // IP softmax over 16 tokens
    float m2 = sip[r];
    m2 = fmaxf(m2, __shfl_xor(m2, 1));
    m2 = fmaxf(m2, __shfl_xor(m2, 2));
    m2 = fmaxf(m2, __shfl_xor(m2, 4));
    m2 = fmaxf(m2, __shfl_xor(m2, 8));
    float pi = __expf(sip[r] - m2);
    float s2 = pi;
    s2 += __shfl_xor(s2, 1);
    s2 += __shfl_xor(s2, 2);
    s2 += __shfl_xor(s2, 4);
    s2 += __shfl_xor(s2, 8);
    P2s[row][lr] = f2b(pi / s2);
    P2s[row][16 + lr] = 0;
  }
  __syncthreads();

  // PV (k-dim 96) and IP-PV (k-dim 32)
  s16x8 ap[3];
#pragma unroll
  for (int ks = 0; ks < 3; ++ks)
    ap[ks] = *(const s16x8*)&Ps[r0 + lr][ks * 32 + lg * 8];
  s16x8 aip = *(const s16x8*)&P2s[r0 + lr][lg * 8];

#pragma unroll
  for (int nt = 0; nt < 4; ++nt) {
    f32x4 o = {};
#pragma unroll
    for (int ks = 0; ks < 3; ++ks) {
      s16x8 bv = *(const s16x8*)&VTs[nt * 16 + lr][ks * 32 + lg * 8];
      o = mfma_bf16(ap[ks], bv, o);
    }
    f32x4 o2 = {};
    {
      s16x8 bv = *(const s16x8*)&VipTs[nt * 16 + lr][lg * 8];
      o2 = mfma_bf16(aip, bv, o2);
    }
#pragma unroll
    for (int r = 0; r < 4; ++r) {
      size_t gi = (size_t)(m0 + r0 + lg * 4 + r) * 1280 + h * 64 + nt * 16 + lr;
      Oattn[gi] = f2b(o[r]);
      Oip[gi] = f2b(o2[r]);
    }
  }
}

// ---------------- launch ----------------
extern "C" void kernel_launch(void* const* d_in, const int* in_sizes, int n_in,
                              void* d_out, int out_size, void* d_ws, size_t ws_size,
                              hipStream_t stream) {
  (void)in_sizes; (void)n_in; (void)out_size; (void)ws_size;
  const float* hs   = (const float*)d_in[0];
  const float* ehs  = (const float*)d_in[1];
  const float* iph  = (const float*)d_in[2];
  const float* mask = (const float*)d_in[3];
  const float* Wq   = (const float*)d_in[4];
  const float* Wk   = (const float*)d_in[5];
  const float* Wv   = (const float*)d_in[6];
  const float* Wo   = (const float*)d_in[7];
  const float* bo   = (const float*)d_in[8];
  const float* Wkip = (const float*)d_in[9];
  const float* Wvip = (const float*)d_in[10];
  float* out = (float*)d_out;

  char* ws = (char*)d_ws;
  size_t off = 0;
  auto alloc = [&](size_t bytes) {
    char* p = ws + off;
    off += (bytes + 255) & ~(size_t)255;
    return p;
  };
  unsigned short* hsb   = (unsigned short*)alloc(16384ull * 1280 * 2);  // reused as attn_out
  unsigned short* qbuf  = (unsigned short*)alloc(16384ull * 1280 * 2);
  unsigned short* ipout = (unsigned short*)alloc(16384ull * 1280 * 2);
  unsigned short* WqT   = (unsigned short*)alloc(1280ull * 1280 * 2);
  unsigned short* WoT   = (unsigned short*)alloc(1280ull * 1280 * 2);
  unsigned short* WkT   = (unsigned short*)alloc(1280ull * 2048 * 2);
  unsigned short* WvT   = (unsigned short*)alloc(1280ull * 2048 * 2);
  unsigned short* WkipT = (unsigned short*)alloc(1280ull * 2048 * 2);
  unsigned short* WvipT = (unsigned short*)alloc(1280ull * 2048 * 2);
  unsigned short* ehsb  = (unsigned short*)alloc(308ull * 2048 * 2);
  unsigned short* ipb   = (unsigned short*)alloc(64ull * 2048 * 2);
  unsigned short* kbuf  = (unsigned short*)alloc(308ull * 1280 * 2);
  unsigned short* vbuf  = (unsigned short*)alloc(308ull * 1280 * 2);
  unsigned short* kipb  = (unsigned short*)alloc(64ull * 1280 * 2);
  unsigned short* vipb  = (unsigned short*)alloc(64ull * 1280 * 2);

  // fp32 -> bf16
  k_f32_to_bf16<<<(16384 * 1280 / 4 + 255) / 256, 256, 0, stream>>>(hs, hsb, 16384 * 1280 / 4);
  k_f32_to_bf16<<<(308 * 2048 / 4 + 255) / 256, 256, 0, stream>>>(ehs, ehsb, 308 * 2048 / 4);
  k_f32_to_bf16<<<(64 * 2048 / 4 + 255) / 256, 256, 0, stream>>>(iph, ipb, 64 * 2048 / 4);
  // weight transposes (to [N][K] bf16)
  k_transpose_w<<<dim3(40, 40), 256, 0, stream>>>(Wq, WqT, 1280, 1280);
  k_transpose_w<<<dim3(40, 40), 256, 0, stream>>>(Wo, WoT, 1280, 1280);
  k_transpose_w<<<dim3(40, 64), 256, 0, stream>>>(Wk, WkT, 2048, 1280);
  k_transpose_w<<<dim3(40, 64), 256, 0, stream>>>(Wv, WvT, 2048, 1280);
  k_transpose_w<<<dim3(40, 64), 256, 0, stream>>>(Wkip, WkipT, 2048, 1280);
  k_transpose_w<<<dim3(40, 64), 256, 0, stream>>>(Wvip, WvipT, 2048, 1280);

  // projections (scale 1/8 baked into Q)
  k_gemm_bt<0><<<dim3(10, 128), 256, 0, stream>>>(hsb, WqT, 16384, 1280, 1280, 0.125f,
                                                  qbuf, nullptr, nullptr, nullptr);
  k_gemm_bt<0><<<dim3(10, 3), 256, 0, stream>>>(ehsb, WkT, 308, 1280, 2048, 1.f,
                                                kbuf, nullptr, nullptr, nullptr);
  k_gemm_bt<0><<<dim3(10, 3), 256, 0, stream>>>(ehsb, WvT, 308, 1280, 2048, 1.f,
                                                vbuf, nullptr, nullptr, nullptr);
  k_gemm_bt<0><<<dim3(10, 1), 256, 0, stream>>>(ipb, WkipT, 64, 1280, 2048, 1.f,
                                                kipb, nullptr, nullptr, nullptr);
  k_gemm_bt<0><<<dim3(10, 1), 256, 0, stream>>>(ipb, WvipT, 64, 1280, 2048, 1.f,
                                                vipb, nullptr, nullptr, nullptr);

  // fused attention (main + IP). attn_out overwrites hsb (no longer needed).
  k_attn<<<dim3(64, 20, 4), 256, 0, stream>>>(qbuf, kbuf, vbuf, kipb, vipb, mask, hsb, ipout);

  // out = attn_out @ Wo + bo + ip_out
  k_gemm_bt<1><<<dim3(10, 128), 256, 0, stream>>>(hsb, WoT, 16384, 1280, 1280, 1.f,
                                                  nullptr, out, bo, ipout);
}

// Round 2
// 351.957 us; speedup vs baseline: 1.6489x; 1.6489x over previous
//
#include <hip/hip_runtime.h>

typedef __attribute__((ext_vector_type(4))) float f32x4;
typedef __attribute__((ext_vector_type(8))) short s16x8;
typedef __attribute__((ext_vector_type(8))) __bf16 bf16x8;
typedef unsigned short u16;

__device__ __forceinline__ u16 f2b(float f) {
  union { float f; unsigned u; } x; x.f = f;
  unsigned r = x.u + 0x7fffu + ((x.u >> 16) & 1u);
  return (u16)(r >> 16);
}
__device__ __forceinline__ float b2f(u16 u) {
  union { unsigned u; float f; } x; x.u = ((unsigned)u) << 16;
  return x.f;
}
__device__ __forceinline__ void gld16(const void* g, void* l) {
  __builtin_amdgcn_global_load_lds(
      (const __attribute__((address_space(1))) unsigned int*)g,
      (__attribute__((address_space(3))) unsigned int*)l, 16, 0, 0);
}
__device__ __forceinline__ f32x4 mfma_bf16(s16x8 a, s16x8 b, f32x4 c) {
  return __builtin_amdgcn_mfma_f32_16x16x32_bf16(
      __builtin_bit_cast(bf16x8, a), __builtin_bit_cast(bf16x8, b), c, 0, 0, 0);
}

// ---------------- fused fp32->bf16 conversion (all three activations) ----------------
__global__ void k_convert_all(const float* __restrict__ hs, const float* __restrict__ ehs,
                              const float* __restrict__ iph,
                              u16* __restrict__ hsb, u16* __restrict__ ehsb,
                              u16* __restrict__ ipb) {
  const int n1 = 16384 * 1280 / 4, n2 = 308 * 2048 / 4, n3 = 64 * 2048 / 4;
  int i = blockIdx.x * blockDim.x + threadIdx.x;
  const float* src; u16* dst; int j = i;
  if (i < n1) { src = hs; dst = hsb; }
  else if (i < n1 + n2) { src = ehs; dst = ehsb; j = i - n1; }
  else if (i < n1 + n2 + n3) { src = iph; dst = ipb; j = i - n1 - n2; }
  else return;
  float4 v = ((const float4*)src)[j];
  ushort4 o;
  o.x = f2b(v.x); o.y = f2b(v.y); o.z = f2b(v.z); o.w = f2b(v.w);
  ((ushort4*)dst)[j] = o;
}

// ---------------- weight transpose: W [K][N] fp32 -> WT [N][K] bf16 ----------------
__device__ __forceinline__ void transpose_tile(const float* __restrict__ W,
                                               u16* __restrict__ WT, int K, int N) {
  __shared__ float tile[32][33];
  int n0 = blockIdx.x * 32, k0 = blockIdx.y * 32;
  int tx = threadIdx.x & 31, ty = threadIdx.x >> 5;
#pragma unroll
  for (int i = 0; i < 32; i += 8)
    tile[ty + i][tx] = W[(size_t)(k0 + ty + i) * N + n0 + tx];
  __syncthreads();
#pragma unroll
  for (int i = 0; i < 32; i += 8)
    WT[(size_t)(n0 + ty + i) * K + k0 + tx] = f2b(tile[tx][ty + i]);
}

__global__ void k_transpose4(const float* W0, const float* W1, const float* W2,
                             const float* W3, u16* T0, u16* T1, u16* T2, u16* T3,
                             int K, int N) {
  int z = blockIdx.z;
  const float* W = (z == 0) ? W0 : (z == 1) ? W1 : (z == 2) ? W2 : W3;
  u16* T = (z == 0) ? T0 : (z == 1) ? T1 : (z == 2) ? T2 : T3;
  transpose_tile(W, T, K, N);
}
__global__ void k_transpose2(const float* W0, const float* W1, u16* T0, u16* T1,
                             int K, int N) {
  int z = blockIdx.z;
  transpose_tile(z ? W1 : W0, z ? T1 : T0, K, N);
}

// ---------------- GEMM core: C[M,N] = A[M,K](bf16) * BT[N,K](bf16)^T ----------------
// EPI 0: outb = bf16(acc*alpha).  EPI 1: outf = acc + bias[n] + b2f(ipadd[m,n]).
template <int EPI>
__device__ __forceinline__ void gemm_core(
    const u16* __restrict__ A, const u16* __restrict__ BT,
    int M, int N, int K, float alpha, u16* __restrict__ outb,
    float* __restrict__ outf, const float* __restrict__ bias,
    const u16* __restrict__ ipadd, int m0, int n0) {
  const int tid = threadIdx.x;
  const int l = tid & 63;
  const int w = tid >> 6;
  const int wr = w >> 1, wc = w & 1;
  __shared__ u16 As[128 * 32];
  __shared__ u16 Bs[128 * 32];
  f32x4 acc[4][4] = {};

  const int o0 = tid * 16;
  const int o1 = o0 + 4096;
  const int ra0 = o0 >> 6, ca0 = (o0 & 63) >> 1;
  const int ra1 = o1 >> 6, ca1 = (o1 & 63) >> 1;
  int ga0 = m0 + ra0; if (ga0 >= M) ga0 = M - 1;
  int ga1 = m0 + ra1; if (ga1 >= M) ga1 = M - 1;
  const u16* Ar0 = A + (size_t)ga0 * K + ca0;
  const u16* Ar1 = A + (size_t)ga1 * K + ca1;
  const u16* Br0 = BT + (size_t)(n0 + ra0) * K + ca0;
  const u16* Br1 = BT + (size_t)(n0 + ra1) * K + ca1;

  for (int k0 = 0; k0 < K; k0 += 32) {
    gld16(Ar0 + k0, &As[o0 >> 1]);
    gld16(Ar1 + k0, &As[o1 >> 1]);
    gld16(Br0 + k0, &Bs[o0 >> 1]);
    gld16(Br1 + k0, &Bs[o1 >> 1]);
    __syncthreads();
    s16x8 af[4], bfr[4];
#pragma unroll
    for (int mi = 0; mi < 4; ++mi)
      af[mi] = *(const s16x8*)&As[(wr * 64 + mi * 16 + (l & 15)) * 32 + (l >> 4) * 8];
#pragma unroll
    for (int ni = 0; ni < 4; ++ni)
      bfr[ni] = *(const s16x8*)&Bs[(wc * 64 + ni * 16 + (l & 15)) * 32 + (l >> 4) * 8];
#pragma unroll
    for (int mi = 0; mi < 4; ++mi)
#pragma unroll
      for (int ni = 0; ni < 4; ++ni)
        acc[mi][ni] = mfma_bf16(af[mi], bfr[ni], acc[mi][ni]);
    __syncthreads();
  }

#pragma unroll
  for (int mi = 0; mi < 4; ++mi) {
    const int mbase = m0 + wr * 64 + mi * 16 + (l >> 4) * 4;
#pragma unroll
    for (int ni = 0; ni < 4; ++ni) {
      const int ncol = n0 + wc * 64 + ni * 16 + (l & 15);
#pragma unroll
      for (int r = 0; r < 4; ++r) {
        int m = mbase + r;
        if (m < M) {
          if constexpr (EPI == 0) {
            outb[(size_t)m * N + ncol] = f2b(acc[mi][ni][r] * alpha);
          } else {
            outf[(size_t)m * N + ncol] =
                acc[mi][ni][r] + bias[ncol] + b2f(ipadd[(size_t)m * N + ncol]);
          }
        }
      }
    }
  }
}

template <int EPI>
__global__ __launch_bounds__(256) void k_gemm_bt(
    const u16* __restrict__ A, const u16* __restrict__ BT,
    int M, int N, int K, float alpha, u16* __restrict__ outb,
    float* __restrict__ outf, const float* __restrict__ bias,
    const u16* __restrict__ ipadd) {
  gemm_core<EPI>(A, BT, M, N, K, alpha, outb, outf, bias, ipadd,
                 blockIdx.y * 128, blockIdx.x * 128);
}

// the four K/V projections in one launch (z selects)
__global__ __launch_bounds__(256) void k_gemm_small4(
    const u16* __restrict__ ehsb, const u16* __restrict__ ipb,
    const u16* __restrict__ WkT, const u16* __restrict__ WvT,
    const u16* __restrict__ WkipT, const u16* __restrict__ WvipT,
    u16* kbuf, u16* vbuf, u16* kipb, u16* vipb) {
  const int z = blockIdx.z;
  const int M = (z < 2) ? 308 : 64;
  const int m0 = blockIdx.y * 128;
  if (m0 >= M) return;
  const u16* A = (z < 2) ? ehsb : ipb;
  const u16* BT = (z == 0) ? WkT : (z == 1) ? WvT : (z == 2) ? WkipT : WvipT;
  u16* out = (z == 0) ? kbuf : (z == 1) ? vbuf : (z == 2) ? kipb : vipb;
  gemm_core<0>(A, BT, M, 1280, 2048, 1.f, out, nullptr, nullptr, nullptr,
               m0, blockIdx.x * 128);
}

// ---------------- fused attention (main + IP stream) ----------------
// grid (32, 20, 4), 512 threads = 8 waves, 128 q-rows/block, 16 rows/wave.
// KV arena rows: 0..76 K, 77..79 zero, 80..95 Kip, 96..172 V, 173..175 zero,
// 176..191 Vip. Segment-XOR swizzle: 16B segment s of row stored at s^((row>>3)&3).
__global__ __launch_bounds__(512, 4) void k_attn(
    const u16* __restrict__ Q,    // [16384][1280], pre-scaled by 1/8
    const u16* __restrict__ Kb,   // [308][1280]
    const u16* __restrict__ Vb,
    const u16* __restrict__ Kip,  // [64][1280]
    const u16* __restrict__ Vip,
    const float* __restrict__ mask,  // [4096][77]
    u16* __restrict__ Oattn,      // [16384][1280] bf16
    u16* __restrict__ Oip) {
  const int qt = blockIdx.x, h = blockIdx.y, b = blockIdx.z;
  const int tid = threadIdx.x, l = tid & 63, w = tid >> 6;
  const int lr = l & 15, lg = l >> 4;
  const int r0 = w * 16;
  const int m0 = b * 4096 + qt * 128;

  __shared__ u16 KV[192][72];    // 27648 B
  __shared__ u16 Ps[128][104];   // 26624 B
  __shared__ u16 P2s[128][40];   // 10240 B

  // Q fragments direct from global (4 lanes cover a contiguous 128B row segment)
  const u16* qrow = Q + (size_t)(m0 + r0 + lr) * 1280 + h * 64;
  s16x8 aq0 = *(const s16x8*)(qrow + lg * 8);
  s16x8 aq1 = *(const s16x8*)(qrow + 32 + lg * 8);

  // stage K / Kip / V / Vip row-major (coalesced int4), seg-XOR swizzled
  for (int s = tid; s < 192 * 8; s += 512) {
    const int row = s >> 3, seg = s & 7;
    int4 v = {0, 0, 0, 0};
    const u16* src = nullptr;
    if (row < 77)       src = Kb  + (size_t)(b * 77 + row) * 1280 + h * 64 + seg * 8;
    else if (row < 80)  src = nullptr;
    else if (row < 96)  src = Kip + (size_t)(b * 16 + row - 80) * 1280 + h * 64 + seg * 8;
    else if (row < 173) src = Vb  + (size_t)(b * 77 + row - 96) * 1280 + h * 64 + seg * 8;
    else if (row < 176) src = nullptr;
    else                src = Vip + (size_t)(b * 16 + row - 176) * 1280 + h * 64 + seg * 8;
    if (src) v = *(const int4*)src;
    *(int4*)&KV[row][(seg ^ ((row >> 3) & 3)) * 8] = v;
  }
  __syncthreads();

  // QK^T: tiles 0..4 = main K (t 0..79, rows 77..79 zero), tile 5 = Kip
  f32x4 sc[5];
  f32x4 sip = {};
#pragma unroll
  for (int t5 = 0; t5 < 6; ++t5) {
    const int trow = t5 * 16 + lr;
    const int q = (trow >> 3) & 3;
    s16x8 b0 = *(const s16x8*)&KV[trow][(lg ^ q) * 8];
    s16x8 b1 = *(const s16x8*)&KV[trow][((lg + 4) ^ q) * 8];
    f32x4 c = {};
    c = mfma_bf16(aq0, b0, c);
    c = mfma_bf16(aq1, b1, c);
    if (t5 < 5) sc[t5] = c; else sip = c;
  }

  // softmax + post-softmax mask (rows live in the 16-lane column group)
#pragma unroll
  for (int r = 0; r < 4; ++r) {
    float mx = fmaxf(fmaxf(fmaxf(sc[0][r], sc[1][r]), fmaxf(sc[2][r], sc[3][r])), sc[4][r]);
    mx = fmaxf(mx, __shfl_xor(mx, 1));
    mx = fmaxf(mx, __shfl_xor(mx, 2));
    mx = fmaxf(mx, __shfl_xor(mx, 4));
    mx = fmaxf(mx, __shfl_xor(mx, 8));
    float p[5], sm = 0.f;
#pragma unroll
    for (int t5 = 0; t5 < 5; ++t5) {
      bool valid = (t5 < 4) | (lr < 13);  // t = t5*16+lr < 77
      p[t5] = valid ? __expf(sc[t5][r] - mx) : 0.f;
      sm += p[t5];
    }
    sm += __shfl_xor(sm, 1);
    sm += __shfl_xor(sm, 2);
    sm += __shfl_xor(sm, 4);
    sm += __shfl_xor(sm, 8);
    const float inv = 1.0f / sm;
    const int row = r0 + lg * 4 + r;
    const int qg = qt * 128 + row;
#pragma unroll
    for (int t5 = 0; t5 < 5; ++t5) {
      int t = t5 * 16 + lr;
      float pf = 0.f;
      if (t < 77) pf = p[t5] * inv * mask[qg * 77 + t];
      Ps[row][t] = f2b(pf);
    }
    Ps[row][80 + lr] = 0;  // zero k 80..95

    // IP softmax (16 tokens)
    float m2 = sip[r];
    m2 = fmaxf(m2, __shfl_xor(m2, 1));
    m2 = fmaxf(m2, __shfl_xor(m2, 2));
    m2 = fmaxf(m2, __shfl_xor(m2, 4));
    m2 = fmaxf(m2, __shfl_xor(m2, 8));
    float pi = __expf(sip[r] - m2);
    float s2 = pi;
    s2 += __shfl_xor(s2, 1);
    s2 += __shfl_xor(s2, 2);
    s2 += __shfl_xor(s2, 4);
    s2 += __shfl_xor(s2, 8);
    P2s[row][lr] = 0;              // k-window 64..79 -> zero
    P2s[row][16 + lr] = f2b(pi / s2);  // k-window 80..95 -> ip probs
  }
  // Ps/P2s are wave-private (each wave owns its 16 rows): no barrier needed.

  // PV: main over t 0..95 (P cols 77..95 zero); IP via k-window t 64..95
  s16x8 ap[3];
#pragma unroll
  for (int ks = 0; ks < 3; ++ks)
    ap[ks] = *(const s16x8*)&Ps[r0 + lr][ks * 32 + lg * 8];
  s16x8 aip = *(const s16x8*)&P2s[r0 + lr][lg * 8];

  f32x4 om[4], oi[4];
#pragma unroll
  for (int nt = 0; nt < 4; ++nt) {
    const int dcol = (nt * 16 + lr) ^ (lg << 3);  // V-region swizzle: q = lg
    f32x4 o = {};
#pragma unroll
    for (int ks = 0; ks < 3; ++ks) {
      s16x8 bv;
#pragma unroll
      for (int j = 0; j < 8; ++j)
        bv[j] = (short)KV[96 + ks * 32 + lg * 8 + j][dcol];
      o = mfma_bf16(ap[ks], bv, o);
    }
    s16x8 bip;
#pragma unroll
    for (int j = 0; j < 8; ++j)
      bip[j] = (short)KV[160 + lg * 8 + j][dcol];
    f32x4 o2 = {};
    o2 = mfma_bf16(aip, bip, o2);
    om[nt] = o;
    oi[nt] = o2;
  }

  __syncthreads();  // all waves done reading KV/Ps: safe to reuse arenas

  u16 (*Om)[72] = (u16(*)[72]) & KV[0][0];
  u16 (*Oi)[72] = (u16(*)[72]) & Ps[0][0];
#pragma unroll
  for (int nt = 0; nt < 4; ++nt)
#pragma unroll
    for (int r = 0; r < 4; ++r) {
      const int row = r0 + lg * 4 + r;
      const int d = nt * 16 + lr;
      Om[row][d] = f2b(om[nt][r]);
      Oi[row][d] = f2b(oi[nt][r]);
    }
  __syncthreads();

  // coalesced int4 stores: 8 lanes cover one row's 128B
  for (int s = tid; s < 128 * 8; s += 512) {
    const int row = s >> 3, seg = s & 7;
    const size_t g = (size_t)(m0 + row) * 1280 + h * 64 + seg * 8;
    *(int4*)(Oattn + g) = *(const int4*)&Om[row][seg * 8];
    *(int4*)(Oip + g) = *(const int4*)&Oi[row][seg * 8];
  }
}

// ---------------- launch ----------------
extern "C" void kernel_launch(void* const* d_in, const int* in_sizes, int n_in,
                              void* d_out, int out_size, void* d_ws, size_t ws_size,
                              hipStream_t stream) {
  (void)in_sizes; (void)n_in; (void)out_size; (void)ws_size;
  const float* hs   = (const float*)d_in[0];
  const float* ehs  = (const float*)d_in[1];
  const float* iph  = (const float*)d_in[2];
  const float* mask = (const float*)d_in[3];
  const float* Wq   = (const float*)d_in[4];
  const float* Wk   = (const float*)d_in[5];
  const float* Wv   = (const float*)d_in[6];
  const float* Wo   = (const float*)d_in[7];
  const float* bo   = (const float*)d_in[8];
  const float* Wkip = (const float*)d_in[9];
  const float* Wvip = (const float*)d_in[10];
  float* out = (float*)d_out;

  char* ws = (char*)d_ws;
  size_t off = 0;
  auto alloc = [&](size_t bytes) {
    char* p = ws + off;
    off += (bytes + 255) & ~(size_t)255;
    return p;
  };
  u16* hsb   = (u16*)alloc(16384ull * 1280 * 2);  // reused as attn_out
  u16* qbuf  = (u16*)alloc(16384ull * 1280 * 2);
  u16* ipout = (u16*)alloc(16384ull * 1280 * 2);
  u16* WqT   = (u16*)alloc(1280ull * 1280 * 2);
  u16* WoT   = (u16*)alloc(1280ull * 1280 * 2);
  u16* WkT   = (u16*)alloc(1280ull * 2048 * 2);
  u16* WvT   = (u16*)alloc(1280ull * 2048 * 2);
  u16* WkipT = (u16*)alloc(1280ull * 2048 * 2);
  u16* WvipT = (u16*)alloc(1280ull * 2048 * 2);
  u16* ehsb  = (u16*)alloc(308ull * 2048 * 2);
  u16* ipb   = (u16*)alloc(64ull * 2048 * 2);
  u16* kbuf  = (u16*)alloc(308ull * 1280 * 2);
  u16* vbuf  = (u16*)alloc(308ull * 1280 * 2);
  u16* kipb  = (u16*)alloc(64ull * 1280 * 2);
  u16* vipb  = (u16*)alloc(64ull * 1280 * 2);

  const int ntot4 = (16384 * 1280 + 308 * 2048 + 64 * 2048) / 4;
  k_convert_all<<<(ntot4 + 255) / 256, 256, 0, stream>>>(hs, ehs, iph, hsb, ehsb, ipb);
  k_transpose4<<<dim3(40, 64, 4), 256, 0, stream>>>(Wk, Wv, Wkip, Wvip,
                                                    WkT, WvT, WkipT, WvipT, 2048, 1280);
  k_transpose2<<<dim3(40, 40, 2), 256, 0, stream>>>(Wq, Wo, WqT, WoT, 1280, 1280);

  // Q projection (scale 1/8 baked in)
  k_gemm_bt<0><<<dim3(10, 128), 256, 0, stream>>>(hsb, WqT, 16384, 1280, 1280, 0.125f,
                                                  qbuf, nullptr, nullptr, nullptr);
  // K/V/Kip/Vip projections in one launch
  k_gemm_small4<<<dim3(10, 3, 4), 256, 0, stream>>>(ehsb, ipb, WkT, WvT, WkipT, WvipT,
                                                    kbuf, vbuf, kipb, vipb);

  // fused attention (main + IP). attn_out overwrites hsb.
  k_attn<<<dim3(32, 20, 4), 512, 0, stream>>>(qbuf, kbuf, vbuf, kipb, vipb, mask,
                                              hsb, ipout);

  // out = attn_out @ Wo + bo + ip_out
  k_gemm_bt<1><<<dim3(10, 128), 256, 0, stream>>>(hsb, WoT, 16384, 1280, 1280, 1.f,
                                                  nullptr, out, bo, ipout);
}

// Round 3
// 305.205 us; speedup vs baseline: 1.9015x; 1.1532x over previous
//
#include <hip/hip_runtime.h>

typedef __attribute__((ext_vector_type(4))) float f32x4;
typedef __attribute__((ext_vector_type(8))) short s16x8;
typedef __attribute__((ext_vector_type(8))) __bf16 bf16x8;
typedef unsigned short u16;

__device__ __forceinline__ u16 f2b(float f) {
  union { float f; unsigned u; } x; x.f = f;
  unsigned r = x.u + 0x7fffu + ((x.u >> 16) & 1u);
  return (u16)(r >> 16);
}
__device__ __forceinline__ float b2f(u16 u) {
  union { unsigned u; float f; } x; x.u = ((unsigned)u) << 16;
  return x.f;
}
__device__ __forceinline__ void gld16(const void* g, void* l) {
  __builtin_amdgcn_global_load_lds(
      (const __attribute__((address_space(1))) unsigned int*)g,
      (__attribute__((address_space(3))) unsigned int*)l, 16, 0, 0);
}
__device__ __forceinline__ f32x4 mfma_bf16(s16x8 a, s16x8 b, f32x4 c) {
  return __builtin_amdgcn_mfma_f32_16x16x32_bf16(
      __builtin_bit_cast(bf16x8, a), __builtin_bit_cast(bf16x8, b), c, 0, 0, 0);
}

// ---------------- fused fp32->bf16 conversion (all three activations) ----------------
__global__ void k_convert_all(const float* __restrict__ hs, const float* __restrict__ ehs,
                              const float* __restrict__ iph,
                              u16* __restrict__ hsb, u16* __restrict__ ehsb,
                              u16* __restrict__ ipb) {
  const int n1 = 16384 * 1280 / 4, n2 = 308 * 2048 / 4, n3 = 64 * 2048 / 4;
  int i = blockIdx.x * blockDim.x + threadIdx.x;
  const float* src; u16* dst; int j = i;
  if (i < n1) { src = hs; dst = hsb; }
  else if (i < n1 + n2) { src = ehs; dst = ehsb; j = i - n1; }
  else if (i < n1 + n2 + n3) { src = iph; dst = ipb; j = i - n1 - n2; }
  else return;
  float4 v = ((const float4*)src)[j];
  ushort4 o;
  o.x = f2b(v.x); o.y = f2b(v.y); o.z = f2b(v.z); o.w = f2b(v.w);
  ((ushort4*)dst)[j] = o;
}

// ---------------- weight transpose: W [K][N] fp32 -> WT [N][K] bf16 ----------------
__device__ __forceinline__ void transpose_tile(const float* __restrict__ W,
                                               u16* __restrict__ WT, int K, int N) {
  __shared__ float tile[32][33];
  int n0 = blockIdx.x * 32, k0 = blockIdx.y * 32;
  int tx = threadIdx.x & 31, ty = threadIdx.x >> 5;
#pragma unroll
  for (int i = 0; i < 32; i += 8)
    tile[ty + i][tx] = W[(size_t)(k0 + ty + i) * N + n0 + tx];
  __syncthreads();
#pragma unroll
  for (int i = 0; i < 32; i += 8)
    WT[(size_t)(n0 + ty + i) * K + k0 + tx] = f2b(tile[tx][ty + i]);
}

__global__ void k_transpose4(const float* W0, const float* W1, const float* W2,
                             const float* W3, u16* T0, u16* T1, u16* T2, u16* T3,
                             int K, int N) {
  int z = blockIdx.z;
  const float* W = (z == 0) ? W0 : (z == 1) ? W1 : (z == 2) ? W2 : W3;
  u16* T = (z == 0) ? T0 : (z == 1) ? T1 : (z == 2) ? T2 : T3;
  transpose_tile(W, T, K, N);
}
__global__ void k_transpose2(const float* W0, const float* W1, u16* T0, u16* T1,
                             int K, int N) {
  int z = blockIdx.z;
  transpose_tile(z ? W1 : W0, z ? T1 : T0, K, N);
}

// ---------------- small-GEMM core (128x128 tile), for K/V projections ----------------
__device__ __forceinline__ void gemm_core0(
    const u16* __restrict__ A, const u16* __restrict__ BT,
    int M, int N, int K, u16* __restrict__ outb, int m0, int n0) {
  const int tid = threadIdx.x;
  const int l = tid & 63;
  const int w = tid >> 6;
  const int wr = w >> 1, wc = w & 1;
  __shared__ u16 As[128 * 32];
  __shared__ u16 Bs[128 * 32];
  f32x4 acc[4][4] = {};

  const int o0 = tid * 16;
  const int o1 = o0 + 4096;
  const int ra0 = o0 >> 6, ca0 = (o0 & 63) >> 1;
  const int ra1 = o1 >> 6, ca1 = (o1 & 63) >> 1;
  int ga0 = m0 + ra0; if (ga0 >= M) ga0 = M - 1;
  int ga1 = m0 + ra1; if (ga1 >= M) ga1 = M - 1;
  const u16* Ar0 = A + (size_t)ga0 * K + ca0;
  const u16* Ar1 = A + (size_t)ga1 * K + ca1;
  const u16* Br0 = BT + (size_t)(n0 + ra0) * K + ca0;
  const u16* Br1 = BT + (size_t)(n0 + ra1) * K + ca1;

  for (int k0 = 0; k0 < K; k0 += 32) {
    gld16(Ar0 + k0, &As[o0 >> 1]);
    gld16(Ar1 + k0, &As[o1 >> 1]);
    gld16(Br0 + k0, &Bs[o0 >> 1]);
    gld16(Br1 + k0, &Bs[o1 >> 1]);
    __syncthreads();
    s16x8 af[4], bfr[4];
#pragma unroll
    for (int mi = 0; mi < 4; ++mi)
      af[mi] = *(const s16x8*)&As[(wr * 64 + mi * 16 + (l & 15)) * 32 + (l >> 4) * 8];
#pragma unroll
    for (int ni = 0; ni < 4; ++ni)
      bfr[ni] = *(const s16x8*)&Bs[(wc * 64 + ni * 16 + (l & 15)) * 32 + (l >> 4) * 8];
#pragma unroll
    for (int mi = 0; mi < 4; ++mi)
#pragma unroll
      for (int ni = 0; ni < 4; ++ni)
        acc[mi][ni] = mfma_bf16(af[mi], bfr[ni], acc[mi][ni]);
    __syncthreads();
  }

#pragma unroll
  for (int mi = 0; mi < 4; ++mi) {
    const int mbase = m0 + wr * 64 + mi * 16 + (l >> 4) * 4;
#pragma unroll
    for (int ni = 0; ni < 4; ++ni) {
      const int ncol = n0 + wc * 64 + ni * 16 + (l & 15);
#pragma unroll
      for (int r = 0; r < 4; ++r) {
        int m = mbase + r;
        if (m < M) outb[(size_t)m * N + ncol] = f2b(acc[mi][ni][r]);
      }
    }
  }
}

// the four K/V projections in one launch (z selects)
__global__ __launch_bounds__(256) void k_gemm_small4(
    const u16* __restrict__ ehsb, const u16* __restrict__ ipb,
    const u16* __restrict__ WkT, const u16* __restrict__ WvT,
    const u16* __restrict__ WkipT, const u16* __restrict__ WvipT,
    u16* kbuf, u16* vbuf, u16* kipb, u16* vipb) {
  const int z = blockIdx.z;
  const int M = (z < 2) ? 308 : 64;
  const int m0 = blockIdx.y * 128;
  if (m0 >= M) return;
  const u16* A = (z < 2) ? ehsb : ipb;
  const u16* BT = (z == 0) ? WkT : (z == 1) ? WvT : (z == 2) ? WkipT : WvipT;
  u16* out = (z == 0) ? kbuf : (z == 1) ? vbuf : (z == 2) ? kipb : vipb;
  gemm_core0(A, BT, M, 1280, 2048, out, m0, blockIdx.x * 128);
}

// ---------------- big GEMM: 256x256 tile, BK=64, dbuf LDS, T1/T2/T3/T5 ----------------
// C[M,N] = A[M,K](bf16) * BT[N,K]^T.  Requires M%256==0, N%256==0, K%64==0,
// grid = (M/256)*(N/256) with grid%8==0 for the XCD swizzle.
// EPI 0: outb = bf16(acc*alpha).  EPI 1: outf = acc + bias[n] + b2f(ipadd[m,n]).
template <int EPI>
__global__ __launch_bounds__(512, 1) void k_gemm256(
    const u16* __restrict__ A, const u16* __restrict__ BT,
    int N, int K, float alpha,
    u16* __restrict__ outb, float* __restrict__ outf,
    const float* __restrict__ bias, const u16* __restrict__ ipadd,
    int nbx) {
  __shared__ u16 lds[65536];  // A: [2][256][64] @0, B: [2][256][64] @32768 (u16 idx)
  const int tid = threadIdx.x, l = tid & 63, w = tid >> 6;
  const int lr = l & 15, lg = l >> 4;
  const int wr = w >> 2, wc = w & 3;

  // bijective chunked XCD swizzle (T1): consecutive logical wgs share A-panels per XCD
  const int nwg = gridDim.x;
  const int q = nwg >> 3, r = nwg & 7;
  const int xcd = blockIdx.x & 7, lid = blockIdx.x >> 3;
  const int wg = (xcd < r) ? (xcd * (q + 1) + lid)
                           : (r * (q + 1) + (xcd - r) * q + lid);
  const int bm0 = (wg / nbx) * 256, bn0 = (wg % nbx) * 256;

  // staging geometry: call j covers rows j*64 + w*8 + (l>>3), 16B slot (l&7).
  // LDS dest linear; global source col pre-permuted (rule #21) to realize the
  // read-side XOR swizzle: element (row, c16) lives at byte row*128 + (c16^(row&7))*16.
  const int srow = w * 8 + (l >> 3);
  const int scol8 = ((l & 7) ^ ((l >> 3) & 7)) * 8;
  const u16* Ag = A + (size_t)(bm0 + srow) * K + scol8;
  const u16* Bg = BT + (size_t)(bn0 + srow) * K + scol8;
  const int sl = (w * 8) * 64 + l * 8;  // u16 idx within a buffer region

  const int KT = K >> 6;
  f32x4 acc[8][4] = {};

  // frag-read slot offsets (u16): slot(ks) = ((ks*4+lg) ^ (lr&7)) * 8
  const int slot0 = (lg ^ (lr & 7)) * 8;
  const int slot1 = ((4 + lg) ^ (lr & 7)) * 8;

  // prologue: stage K-tile 0 into buffer 0
#pragma unroll
  for (int j = 0; j < 4; ++j)
    gld16(Ag + (size_t)j * 64 * K, &lds[j * 4096 + sl]);
#pragma unroll
  for (int j = 0; j < 4; ++j)
    gld16(Bg + (size_t)j * 64 * K, &lds[32768 + j * 4096 + sl]);
  __syncthreads();

  int cur = 0;
  for (int t = 0; t < KT; ++t) {
    // T3 minimum-2-phase: issue next tile's staging FIRST (into the other buffer),
    // compute covers the latency; the tile-end __syncthreads drains vmcnt once.
    if (t + 1 < KT) {
      const int k0 = (t + 1) << 6;
      const int c1 = (cur ^ 1) * 16384;
#pragma unroll
      for (int j = 0; j < 4; ++j)
        gld16(Ag + (size_t)j * 64 * K + k0, &lds[c1 + j * 4096 + sl]);
#pragma unroll
      for (int j = 0; j < 4; ++j)
        gld16(Bg + (size_t)j * 64 * K + k0, &lds[32768 + c1 + j * 4096 + sl]);
    }
    const int ca = cur * 16384;
    const int cb = 32768 + ca;
    s16x8 bfv[4][2], afv[4][2];
#pragma unroll
    for (int ni = 0; ni < 4; ++ni) {
      const int rb = cb + (wc * 64 + ni * 16 + lr) * 64;
      bfv[ni][0] = *(const s16x8*)&lds[rb + slot0];
      bfv[ni][1] = *(const s16x8*)&lds[rb + slot1];
    }
#pragma unroll
    for (int mi = 0; mi < 4; ++mi) {
      const int ra = ca + (wr * 128 + mi * 16 + lr) * 64;
      afv[mi][0] = *(const s16x8*)&lds[ra + slot0];
      afv[mi][1] = *(const s16x8*)&lds[ra + slot1];
    }
    __builtin_amdgcn_s_setprio(1);
#pragma unroll
    for (int mi = 0; mi < 4; ++mi)
#pragma unroll
      for (int ni = 0; ni < 4; ++ni) {
        acc[mi][ni] = mfma_bf16(afv[mi][0], bfv[ni][0], acc[mi][ni]);
        acc[mi][ni] = mfma_bf16(afv[mi][1], bfv[ni][1], acc[mi][ni]);
      }
    __builtin_amdgcn_s_setprio(0);
#pragma unroll
    for (int mi = 0; mi < 4; ++mi) {
      const int ra = ca + (wr * 128 + (mi + 4) * 16 + lr) * 64;
      afv[mi][0] = *(const s16x8*)&lds[ra + slot0];
      afv[mi][1] = *(const s16x8*)&lds[ra + slot1];
    }
    __builtin_amdgcn_s_setprio(1);
#pragma unroll
    for (int mi = 0; mi < 4; ++mi)
#pragma unroll
      for (int ni = 0; ni < 4; ++ni) {
        acc[mi + 4][ni] = mfma_bf16(afv[mi][0], bfv[ni][0], acc[mi + 4][ni]);
        acc[mi + 4][ni] = mfma_bf16(afv[mi][1], bfv[ni][1], acc[mi + 4][ni]);
      }
    __builtin_amdgcn_s_setprio(0);
    __syncthreads();
    cur ^= 1;
  }

  // epilogue
#pragma unroll
  for (int mi = 0; mi < 8; ++mi) {
    const int mrow = bm0 + wr * 128 + mi * 16 + lg * 4;
#pragma unroll
    for (int ni = 0; ni < 4; ++ni) {
      const int ncol = bn0 + wc * 64 + ni * 16 + lr;
#pragma unroll
      for (int rr = 0; rr < 4; ++rr) {
        const size_t idx = (size_t)(mrow + rr) * N + ncol;
        if constexpr (EPI == 0) {
          outb[idx] = f2b(acc[mi][ni][rr] * alpha);
        } else {
          outf[idx] = acc[mi][ni][rr] + bias[ncol] + b2f(ipadd[idx]);
        }
      }
    }
  }
}

// ---------------- fused attention (main + IP stream) ----------------
// grid (32, 20, 4), 512 threads = 8 waves, 128 q-rows/block, 16 rows/wave.
// KV arena rows: 0..76 K, 77..79 zero, 80..95 Kip, 96..172 V, 173..175 zero,
// 176..191 Vip. Segment-XOR swizzle: 16B segment s of row stored at s^((row>>3)&3).
__global__ __launch_bounds__(512, 4) void k_attn(
    const u16* __restrict__ Q,    // [16384][1280], pre-scaled by 1/8
    const u16* __restrict__ Kb,   // [308][1280]
    const u16* __restrict__ Vb,
    const u16* __restrict__ Kip,  // [64][1280]
    const u16* __restrict__ Vip,
    const float* __restrict__ mask,  // [4096][77]
    u16* __restrict__ Oattn,      // [16384][1280] bf16
    u16* __restrict__ Oip) {
  const int qt = blockIdx.x, h = blockIdx.y, b = blockIdx.z;
  const int tid = threadIdx.x, l = tid & 63, w = tid >> 6;
  const int lr = l & 15, lg = l >> 4;
  const int r0 = w * 16;
  const int m0 = b * 4096 + qt * 128;

  __shared__ u16 KV[192][72];
  __shared__ u16 Ps[128][104];
  __shared__ u16 P2s[128][40];

  const u16* qrow = Q + (size_t)(m0 + r0 + lr) * 1280 + h * 64;
  s16x8 aq0 = *(const s16x8*)(qrow + lg * 8);
  s16x8 aq1 = *(const s16x8*)(qrow + 32 + lg * 8);

  for (int s = tid; s < 192 * 8; s += 512) {
    const int row = s >> 3, seg = s & 7;
    int4 v = {0, 0, 0, 0};
    const u16* src = nullptr;
    if (row < 77)       src = Kb  + (size_t)(b * 77 + row) * 1280 + h * 64 + seg * 8;
    else if (row < 80)  src = nullptr;
    else if (row < 96)  src = Kip + (size_t)(b * 16 + row - 80) * 1280 + h * 64 + seg * 8;
    else if (row < 173) src = Vb  + (size_t)(b * 77 + row - 96) * 1280 + h * 64 + seg * 8;
    else if (row < 176) src = nullptr;
    else                src = Vip + (size_t)(b * 16 + row - 176) * 1280 + h * 64 + seg * 8;
    if (src) v = *(const int4*)src;
    *(int4*)&KV[row][(seg ^ ((row >> 3) & 3)) * 8] = v;
  }
  __syncthreads();

  f32x4 sc[5];
  f32x4 sip = {};
#pragma unroll
  for (int t5 = 0; t5 < 6; ++t5) {
    const int trow = t5 * 16 + lr;
    const int qz = (trow >> 3) & 3;
    s16x8 b0 = *(const s16x8*)&KV[trow][(lg ^ qz) * 8];
    s16x8 b1 = *(const s16x8*)&KV[trow][((lg + 4) ^ qz) * 8];
    f32x4 c = {};
    c = mfma_bf16(aq0, b0, c);
    c = mfma_bf16(aq1, b1, c);
    if (t5 < 5) sc[t5] = c; else sip = c;
  }

#pragma unroll
  for (int r = 0; r < 4; ++r) {
    float mx = fmaxf(fmaxf(fmaxf(sc[0][r], sc[1][r]), fmaxf(sc[2][r], sc[3][r])), sc[4][r]);
    mx = fmaxf(mx, __shfl_xor(mx, 1));
    mx = fmaxf(mx, __shfl_xor(mx, 2));
    mx = fmaxf(mx, __shfl_xor(mx, 4));
    mx = fmaxf(mx, __shfl_xor(mx, 8));
    float p[5], sm = 0.f;
#pragma unroll
    for (int t5 = 0; t5 < 5; ++t5) {
      bool valid = (t5 < 4) | (lr < 13);
      p[t5] = valid ? __expf(sc[t5][r] - mx) : 0.f;
      sm += p[t5];
    }
    sm += __shfl_xor(sm, 1);
    sm += __shfl_xor(sm, 2);
    sm += __shfl_xor(sm, 4);
    sm += __shfl_xor(sm, 8);
    const float inv = 1.0f / sm;
    const int row = r0 + lg * 4 + r;
    const int qg = qt * 128 + row;
#pragma unroll
    for (int t5 = 0; t5 < 5; ++t5) {
      int t = t5 * 16 + lr;
      float pf = 0.f;
      if (t < 77) pf = p[t5] * inv * mask[qg * 77 + t];
      Ps[row][t] = f2b(pf);
    }
    Ps[row][80 + lr] = 0;

    float m2 = sip[r];
    m2 = fmaxf(m2, __shfl_xor(m2, 1));
    m2 = fmaxf(m2, __shfl_xor(m2, 2));
    m2 = fmaxf(m2, __shfl_xor(m2, 4));
    m2 = fmaxf(m2, __shfl_xor(m2, 8));
    float pi = __expf(sip[r] - m2);
    float s2 = pi;
    s2 += __shfl_xor(s2, 1);
    s2 += __shfl_xor(s2, 2);
    s2 += __shfl_xor(s2, 4);
    s2 += __shfl_xor(s2, 8);
    P2s[row][lr] = 0;
    P2s[row][16 + lr] = f2b(pi / s2);
  }

  s16x8 ap[3];
#pragma unroll
  for (int ks = 0; ks < 3; ++ks)
    ap[ks] = *(const s16x8*)&Ps[r0 + lr][ks * 32 + lg * 8];
  s16x8 aip = *(const s16x8*)&P2s[r0 + lr][lg * 8];

  f32x4 om[4], oi[4];
#pragma unroll
  for (int nt = 0; nt < 4; ++nt) {
    const int dcol = (nt * 16 + lr) ^ (lg << 3);
    f32x4 o = {};
#pragma unroll
    for (int ks = 0; ks < 3; ++ks) {
      s16x8 bv;
#pragma unroll
      for (int j = 0; j < 8; ++j)
        bv[j] = (short)KV[96 + ks * 32 + lg * 8 + j][dcol];
      o = mfma_bf16(ap[ks], bv, o);
    }
    s16x8 bip;
#pragma unroll
    for (int j = 0; j < 8; ++j)
      bip[j] = (short)KV[160 + lg * 8 + j][dcol];
    f32x4 o2 = {};
    o2 = mfma_bf16(aip, bip, o2);
    om[nt] = o;
    oi[nt] = o2;
  }

  __syncthreads();

  u16 (*Om)[72] = (u16(*)[72]) & KV[0][0];
  u16 (*Oi)[72] = (u16(*)[72]) & Ps[0][0];
#pragma unroll
  for (int nt = 0; nt < 4; ++nt)
#pragma unroll
    for (int r = 0; r < 4; ++r) {
      const int row = r0 + lg * 4 + r;
      const int d = nt * 16 + lr;
      Om[row][d] = f2b(om[nt][r]);
      Oi[row][d] = f2b(oi[nt][r]);
    }
  __syncthreads();

  for (int s = tid; s < 128 * 8; s += 512) {
    const int row = s >> 3, seg = s & 7;
    const size_t g = (size_t)(m0 + row) * 1280 + h * 64 + seg * 8;
    *(int4*)(Oattn + g) = *(const int4*)&Om[row][seg * 8];
    *(int4*)(Oip + g) = *(const int4*)&Oi[row][seg * 8];
  }
}

// ---------------- launch ----------------
extern "C" void kernel_launch(void* const* d_in, const int* in_sizes, int n_in,
                              void* d_out, int out_size, void* d_ws, size_t ws_size,
                              hipStream_t stream) {
  (void)in_sizes; (void)n_in; (void)out_size; (void)ws_size;
  const float* hs   = (const float*)d_in[0];
  const float* ehs  = (const float*)d_in[1];
  const float* iph  = (const float*)d_in[2];
  const float* mask = (const float*)d_in[3];
  const float* Wq   = (const float*)d_in[4];
  const float* Wk   = (const float*)d_in[5];
  const float* Wv   = (const float*)d_in[6];
  const float* Wo   = (const float*)d_in[7];
  const float* bo   = (const float*)d_in[8];
  const float* Wkip = (const float*)d_in[9];
  const float* Wvip = (const float*)d_in[10];
  float* out = (float*)d_out;

  char* ws = (char*)d_ws;
  size_t off = 0;
  auto alloc = [&](size_t bytes) {
    char* p = ws + off;
    off += (bytes + 255) & ~(size_t)255;
    return p;
  };
  u16* hsb   = (u16*)alloc(16384ull * 1280 * 2);  // reused as attn_out
  u16* qbuf  = (u16*)alloc(16384ull * 1280 * 2);
  u16* ipout = (u16*)alloc(16384ull * 1280 * 2);
  u16* WqT   = (u16*)alloc(1280ull * 1280 * 2);
  u16* WoT   = (u16*)alloc(1280ull * 1280 * 2);
  u16* WkT   = (u16*)alloc(1280ull * 2048 * 2);
  u16* WvT   = (u16*)alloc(1280ull * 2048 * 2);
  u16* WkipT = (u16*)alloc(1280ull * 2048 * 2);
  u16* WvipT = (u16*)alloc(1280ull * 2048 * 2);
  u16* ehsb  = (u16*)alloc(308ull * 2048 * 2);
  u16* ipb   = (u16*)alloc(64ull * 2048 * 2);
  u16* kbuf  = (u16*)alloc(308ull * 1280 * 2);
  u16* vbuf  = (u16*)alloc(308ull * 1280 * 2);
  u16* kipb  = (u16*)alloc(64ull * 1280 * 2);
  u16* vipb  = (u16*)alloc(64ull * 1280 * 2);

  const int ntot4 = (16384 * 1280 + 308 * 2048 + 64 * 2048) / 4;
  k_convert_all<<<(ntot4 + 255) / 256, 256, 0, stream>>>(hs, ehs, iph, hsb, ehsb, ipb);
  k_transpose4<<<dim3(40, 64, 4), 256, 0, stream>>>(Wk, Wv, Wkip, Wvip,
                                                    WkT, WvT, WkipT, WvipT, 2048, 1280);
  k_transpose2<<<dim3(40, 40, 2), 256, 0, stream>>>(Wq, Wo, WqT, WoT, 1280, 1280);

  // Q projection (scale 1/8 baked in): 64 x 5 = 320 blocks
  k_gemm256<0><<<320, 512, 0, stream>>>(hsb, WqT, 1280, 1280, 0.125f,
                                        qbuf, nullptr, nullptr, nullptr, 5);
  // K/V/Kip/Vip projections in one launch
  k_gemm_small4<<<dim3(10, 3, 4), 256, 0, stream>>>(ehsb, ipb, WkT, WvT, WkipT, WvipT,
                                                    kbuf, vbuf, kipb, vipb);

  // fused attention (main + IP). attn_out overwrites hsb.
  k_attn<<<dim3(32, 20, 4), 512, 0, stream>>>(qbuf, kbuf, vbuf, kipb, vipb, mask,
                                              hsb, ipout);

  // out = attn_out @ Wo + bo + ip_out
  k_gemm256<1><<<320, 512, 0, stream>>>(hsb, WoT, 1280, 1280, 1.f,
                                        nullptr, out, bo, ipout, 5);
}